// Round 1
// baseline (660.562 us; speedup 1.0000x reference)
//
#include <hip/hip_runtime.h>
#include <hip/hip_bf16.h>
#include <math.h>

// Problem constants
#define L_SEQ 1024
#define D_DIM 512
#define A_DIM 32
#define H_DIM 8
#define F_DIM 2048
#define AH 256      // A_DIM*H_DIM
#define DH 4096     // D_DIM*H_DIM
#define NC 16       // number of chunks
#define CH 64       // chunk length
#define EPS_LN 1e-5f

// ---------------------------------------------------------------------------
// LayerNorm over D (ln0): one block per row
// ---------------------------------------------------------------------------
__global__ __launch_bounds__(256) void ln0_kernel(const float* __restrict__ x,
                                                  const float* __restrict__ w,
                                                  const float* __restrict__ b,
                                                  float* __restrict__ xn) {
    int l = blockIdx.x;
    int tid = threadIdx.x;
    float v0 = x[l * D_DIM + tid];
    float v1 = x[l * D_DIM + 256 + tid];
    float s = v0 + v1, s2 = v0 * v0 + v1 * v1;
    // wave reduce (64 lanes)
    for (int off = 32; off > 0; off >>= 1) {
        s += __shfl_down(s, off);
        s2 += __shfl_down(s2, off);
    }
    __shared__ float red[8];
    int lane = tid & 63, wid = tid >> 6;
    if (lane == 0) { red[wid] = s; red[4 + wid] = s2; }
    __syncthreads();
    float ts = red[0] + red[1] + red[2] + red[3];
    float t2 = red[4] + red[5] + red[6] + red[7];
    float mu = ts / (float)D_DIM;
    float var = t2 / (float)D_DIM - mu * mu;
    float rs = rsqrtf(var + EPS_LN);
    xn[l * D_DIM + tid]       = (v0 - mu) * rs * w[tid] + b[tid];
    xn[l * D_DIM + 256 + tid] = (v1 - mu) * rs * w[256 + tid] + b[256 + tid];
}

// ---------------------------------------------------------------------------
// Generic fp32 tiled GEMM: C[M,N] = A[M,K] @ B[K,N] (+bias, epilogue)
// EPI: 0 = exp(clip(.+bias)), 1 = +bias, 2 = relu(.+bias), 3 = relu(.+bias)+res
// ---------------------------------------------------------------------------
template <int EPI>
__global__ __launch_bounds__(256) void gemm_f32(const float* __restrict__ A,
                                                const float* __restrict__ B,
                                                const float* __restrict__ bias,
                                                const float* __restrict__ res,
                                                float* __restrict__ C,
                                                int M, int N, int K) {
    __shared__ float As[16][68]; // [k][m], padded
    __shared__ float Bs[16][68]; // [k][n], padded
    int bm = blockIdx.y * 64, bn = blockIdx.x * 64;
    int tid = threadIdx.x;
    int tx = tid & 15, ty = tid >> 4;
    int arow = tid >> 2, akq = (tid & 3) * 4;
    int brow = tid >> 4, bcol = (tid & 15) * 4;
    float acc[4][4] = {};
    for (int k0 = 0; k0 < K; k0 += 16) {
        float4 av = *(const float4*)(&A[(size_t)(bm + arow) * K + k0 + akq]);
        float4 bv = *(const float4*)(&B[(size_t)(k0 + brow) * N + bn + bcol]);
        __syncthreads();
        As[akq + 0][arow] = av.x;
        As[akq + 1][arow] = av.y;
        As[akq + 2][arow] = av.z;
        As[akq + 3][arow] = av.w;
        *(float4*)&Bs[brow][bcol] = bv;
        __syncthreads();
#pragma unroll
        for (int kk = 0; kk < 16; ++kk) {
            float4 a4 = *(const float4*)&As[kk][ty * 4];
            float4 b4 = *(const float4*)&Bs[kk][tx * 4];
            float aa[4] = {a4.x, a4.y, a4.z, a4.w};
            float bb[4] = {b4.x, b4.y, b4.z, b4.w};
#pragma unroll
            for (int i = 0; i < 4; ++i)
#pragma unroll
                for (int j = 0; j < 4; ++j) acc[i][j] += aa[i] * bb[j];
        }
    }
#pragma unroll
    for (int i = 0; i < 4; ++i) {
        int m = bm + ty * 4 + i;
#pragma unroll
        for (int j = 0; j < 4; ++j) {
            int n = bn + tx * 4 + j;
            float r = acc[i][j] + bias[n];
            if (EPI == 0) r = expf(fminf(fmaxf(r, -10.f), 10.f));
            if (EPI == 2) r = fmaxf(r, 0.f);
            if (EPI == 3) r = fmaxf(r, 0.f) + res[(size_t)m * N + n];
            C[(size_t)m * N + n] = r;
        }
    }
}

// ---------------------------------------------------------------------------
// Pass A: per-chunk KV sums  S[c][a][h][d] = sum_{l in c} k[l,a,h]*v[l,d,h]
// grid (NC, H, 2), block 256 (d within half)
// ---------------------------------------------------------------------------
__global__ __launch_bounds__(256) void passA_kernel(const float* __restrict__ k,
                                                    const float* __restrict__ v,
                                                    float* __restrict__ S) {
    int c = blockIdx.x, h = blockIdx.y, dg = blockIdx.z;
    int tid = threadIdx.x;
    int d = dg * 256 + tid;
    __shared__ float ks[CH][A_DIM];
    for (int e = tid; e < CH * A_DIM; e += 256) {
        int l = e >> 5, a = e & 31;
        ks[l][a] = k[(c * CH + l) * AH + a * H_DIM + h];
    }
    __syncthreads();
    float acc[A_DIM];
#pragma unroll
    for (int a = 0; a < A_DIM; ++a) acc[a] = 0.f;
    for (int l = 0; l < CH; ++l) {
        float vv = v[(size_t)(c * CH + l) * DH + d * H_DIM + h];
#pragma unroll
        for (int a = 0; a < A_DIM; ++a) acc[a] += ks[l][a] * vv;
    }
#pragma unroll
    for (int a = 0; a < A_DIM; ++a)
        S[(size_t)((c * A_DIM + a) * H_DIM + h) * D_DIM + d] = acc[a];
}

// ---------------------------------------------------------------------------
// Pass B: exclusive prefix over chunks for every (a,h,d)
// ---------------------------------------------------------------------------
__global__ __launch_bounds__(256) void scanS_kernel(const float* __restrict__ S,
                                                    float* __restrict__ P) {
    int j = blockIdx.x * 256 + threadIdx.x; // 0..131071
    float run = 0.f;
    for (int c = 0; c < NC; ++c) {
        P[(size_t)c * (A_DIM * H_DIM * D_DIM) + j] = run;
        run += S[(size_t)c * (A_DIM * H_DIM * D_DIM) + j];
    }
}

// ---------------------------------------------------------------------------
// Pass C: within-chunk recurrence -> qkv[l, d*H+h]
// grid (NC, H, 2), block 256 (d)
// ---------------------------------------------------------------------------
__global__ __launch_bounds__(256) void passC_kernel(const float* __restrict__ q,
                                                    const float* __restrict__ k,
                                                    const float* __restrict__ v,
                                                    const float* __restrict__ P,
                                                    float* __restrict__ qkv) {
    int c = blockIdx.x, h = blockIdx.y, dg = blockIdx.z;
    int tid = threadIdx.x;
    int d = dg * 256 + tid;
    __shared__ float ks[CH][A_DIM];
    __shared__ float qs[CH][A_DIM];
    for (int e = tid; e < CH * A_DIM; e += 256) {
        int l = e >> 5, a = e & 31;
        int gi = (c * CH + l) * AH + a * H_DIM + h;
        ks[l][a] = k[gi];
        qs[l][a] = q[gi];
    }
    __syncthreads();
    float st[A_DIM];
#pragma unroll
    for (int a = 0; a < A_DIM; ++a)
        st[a] = P[(size_t)((c * A_DIM + a) * H_DIM + h) * D_DIM + d];
    for (int l = 0; l < CH; ++l) {
        float vv = v[(size_t)(c * CH + l) * DH + d * H_DIM + h];
        float s = 0.f;
#pragma unroll
        for (int a = 0; a < A_DIM; ++a) {
            st[a] += ks[l][a] * vv;
            s += qs[l][a] * st[a];
        }
        qkv[(size_t)(c * CH + l) * DH + d * H_DIM + h] = s;
    }
}

// ---------------------------------------------------------------------------
// den path: chunk sums of k, scan, kcum, den
// ---------------------------------------------------------------------------
__global__ __launch_bounds__(256) void ka_kernel(const float* __restrict__ k, float* __restrict__ Ka) {
    int c = blockIdx.x, t = threadIdx.x;
    float s = 0.f;
    for (int l = 0; l < CH; ++l) s += k[(c * CH + l) * AH + t];
    Ka[c * AH + t] = s;
}

__global__ __launch_bounds__(256) void kp_kernel(const float* __restrict__ Ka, float* __restrict__ Kp) {
    int t = threadIdx.x;
    float run = 0.f;
    for (int c = 0; c < NC; ++c) {
        Kp[c * AH + t] = run;
        run += Ka[c * AH + t];
    }
}

__global__ __launch_bounds__(256) void kcum_kernel(const float* __restrict__ k,
                                                   const float* __restrict__ Kp,
                                                   float* __restrict__ kc) {
    int c = blockIdx.x, t = threadIdx.x;
    float run = Kp[c * AH + t];
    for (int l = 0; l < CH; ++l) {
        int gi = (c * CH + l) * AH + t;
        run += k[gi];
        kc[gi] = run;
    }
}

__global__ __launch_bounds__(256) void den_kernel(const float* __restrict__ q,
                                                  const float* __restrict__ kc,
                                                  float* __restrict__ den) {
    int idx = blockIdx.x * 256 + threadIdx.x; // L*H = 8192
    int l = idx >> 3, h = idx & 7;
    float s = 0.f;
#pragma unroll
    for (int a = 0; a < A_DIM; ++a)
        s += q[l * AH + a * H_DIM + h] * kc[l * AH + a * H_DIM + h];
    den[idx] = s;
}

// ---------------------------------------------------------------------------
// LN1 over (D,H) jointly + broadcast residual:  y[l, d*H+h] = x[l,d] + LN(qkv/den)
// ---------------------------------------------------------------------------
__global__ __launch_bounds__(256) void ln1_kernel(const float* __restrict__ qkv,
                                                  const float* __restrict__ den,
                                                  const float* __restrict__ x,
                                                  const float* __restrict__ w,
                                                  const float* __restrict__ b,
                                                  float* __restrict__ y) {
    int l = blockIdx.x, tid = threadIdx.x;
    __shared__ float dsh[8];
    if (tid < 8) dsh[tid] = den[l * H_DIM + tid];
    __syncthreads();
    float t[16];
    float s = 0.f, s2 = 0.f;
#pragma unroll
    for (int j = 0; j < 16; ++j) {
        int dh = j * 256 + tid;
        float val = qkv[(size_t)l * DH + dh] / dsh[tid & 7];
        t[j] = val;
        s += val;
        s2 += val * val;
    }
    for (int off = 32; off > 0; off >>= 1) {
        s += __shfl_down(s, off);
        s2 += __shfl_down(s2, off);
    }
    __shared__ float red[8];
    int lane = tid & 63, wid = tid >> 6;
    if (lane == 0) { red[wid] = s; red[4 + wid] = s2; }
    __syncthreads();
    float ts = red[0] + red[1] + red[2] + red[3];
    float t2 = red[4] + red[5] + red[6] + red[7];
    float mu = ts / (float)DH;
    float var = t2 / (float)DH - mu * mu;
    float rs = rsqrtf(var + EPS_LN);
#pragma unroll
    for (int j = 0; j < 16; ++j) {
        int dh = j * 256 + tid;
        y[(size_t)l * DH + dh] = x[l * D_DIM + (dh >> 3)] + (t[j] - mu) * rs * w[dh] + b[dh];
    }
}

// ---------------------------------------------------------------------------
// Launch
// ---------------------------------------------------------------------------
extern "C" void kernel_launch(void* const* d_in, const int* in_sizes, int n_in,
                              void* d_out, int out_size, void* d_ws, size_t ws_size,
                              hipStream_t stream) {
    const float* x     = (const float*)d_in[0];
    const float* ln0_w = (const float*)d_in[1];
    const float* ln0_b = (const float*)d_in[2];
    const float* ln1_w = (const float*)d_in[3];
    const float* ln1_b = (const float*)d_in[4];
    const float* qw    = (const float*)d_in[5];
    const float* qb    = (const float*)d_in[6];
    const float* kw    = (const float*)d_in[7];
    const float* kb    = (const float*)d_in[8];
    const float* vw    = (const float*)d_in[9];
    const float* vb    = (const float*)d_in[10];
    const float* w1    = (const float*)d_in[11];
    const float* b1    = (const float*)d_in[12];
    const float* w2    = (const float*)d_in[13];
    const float* b2    = (const float*)d_in[14];
    float* out = (float*)d_out;

    float* ws = (float*)d_ws;
    float* xn   = ws;                       // L*D       = 524288
    float* q    = xn + L_SEQ * D_DIM;       // L*AH      = 262144
    float* kbuf = q + L_SEQ * AH;           // L*AH      = 262144
    float* v    = kbuf + L_SEQ * AH;        // L*DH      = 4194304
    float* S    = v + (size_t)L_SEQ * DH;   // NC*A*H*D  = 2097152
    float* P    = S + (size_t)NC * A_DIM * H_DIM * D_DIM;   // 2097152
    float* qkv  = P + (size_t)NC * A_DIM * H_DIM * D_DIM;   // L*DH = 4194304
    float* Ka   = qkv + (size_t)L_SEQ * DH; // NC*AH = 4096
    float* Kp   = Ka + NC * AH;             // 4096
    float* kc   = Kp + NC * AH;             // L*AH = 262144
    float* den  = kc + L_SEQ * AH;          // L*H = 8192
    float* y    = v;                        // alias: v dead after passC
    float* h1   = S;                        // alias: S dead after scanS

    // 1) LN0
    ln0_kernel<<<L_SEQ, 256, 0, stream>>>(x, ln0_w, ln0_b, xn);
    // 2) q = exp(clip(xn@qw + qb)), k likewise
    gemm_f32<0><<<dim3(AH / 64, L_SEQ / 64), 256, 0, stream>>>(xn, qw, qb, nullptr, q, L_SEQ, AH, D_DIM);
    gemm_f32<0><<<dim3(AH / 64, L_SEQ / 64), 256, 0, stream>>>(xn, kw, kb, nullptr, kbuf, L_SEQ, AH, D_DIM);
    // 3) v = x@vw + vb  (raw x!)
    gemm_f32<1><<<dim3(DH / 64, L_SEQ / 64), 256, 0, stream>>>(x, vw, vb, nullptr, v, L_SEQ, DH, D_DIM);
    // 4) chunked KV scan
    passA_kernel<<<dim3(NC, H_DIM, 2), 256, 0, stream>>>(kbuf, v, S);
    scanS_kernel<<<(A_DIM * H_DIM * D_DIM) / 256, 256, 0, stream>>>(S, P);
    passC_kernel<<<dim3(NC, H_DIM, 2), 256, 0, stream>>>(q, kbuf, v, P, qkv);
    // 5) den path
    ka_kernel<<<NC, 256, 0, stream>>>(kbuf, Ka);
    kp_kernel<<<1, 256, 0, stream>>>(Ka, Kp);
    kcum_kernel<<<NC, 256, 0, stream>>>(kbuf, Kp, kc);
    den_kernel<<<(L_SEQ * H_DIM) / 256, 256, 0, stream>>>(q, kc, den);
    // 6) LN1 + residual broadcast -> y
    ln1_kernel<<<L_SEQ, 256, 0, stream>>>(qkv, den, x, ln1_w, ln1_b, y);
    // 7) MLP
    gemm_f32<2><<<dim3(F_DIM / 64, L_SEQ / 64), 256, 0, stream>>>(y, w1, b1, nullptr, h1, L_SEQ, F_DIM, DH);
    gemm_f32<3><<<dim3(D_DIM / 64, L_SEQ / 64), 256, 0, stream>>>(h1, w2, b2, x, out, L_SEQ, D_DIM, F_DIM);

    (void)in_sizes; (void)n_in; (void)out_size; (void)ws_size;
}

// Round 2
// 338.011 us; speedup vs baseline: 1.9543x; 1.9543x over previous
//
#include <hip/hip_runtime.h>
#include <hip/hip_bf16.h>
#include <math.h>

#define L_SEQ 1024
#define D_DIM 512
#define A_DIM 32
#define H_DIM 8
#define F_DIM 2048
#define AH 256
#define DH 4096
#define NC 16
#define CH 64
#define EPS_LN 1e-5f

typedef __attribute__((ext_vector_type(8))) short short8;
typedef __attribute__((ext_vector_type(4))) float floatx4;

#define ASYNC_COPY16(gp, lp)                                                     \
    __builtin_amdgcn_global_load_lds(                                            \
        (const __attribute__((address_space(1))) void*)(const void*)(gp),        \
        (__attribute__((address_space(3))) void*)(void*)(lp), 16, 0, 0)

// ---------------------------------------------------------------------------
// LN0: per-row layernorm over D; writes bf16 xn and bf16 copy of x
// ---------------------------------------------------------------------------
__global__ __launch_bounds__(256) void ln0_kernel(const float* __restrict__ x,
                                                  const float* __restrict__ w,
                                                  const float* __restrict__ b,
                                                  __hip_bfloat16* __restrict__ xn,
                                                  __hip_bfloat16* __restrict__ xb) {
    int l = blockIdx.x;
    int tid = threadIdx.x;
    float v0 = x[l * D_DIM + tid];
    float v1 = x[l * D_DIM + 256 + tid];
    float s = v0 + v1, s2 = v0 * v0 + v1 * v1;
    for (int off = 32; off > 0; off >>= 1) {
        s += __shfl_down(s, off);
        s2 += __shfl_down(s2, off);
    }
    __shared__ float red[8];
    int lane = tid & 63, wid = tid >> 6;
    if (lane == 0) { red[wid] = s; red[4 + wid] = s2; }
    __syncthreads();
    float ts = red[0] + red[1] + red[2] + red[3];
    float t2 = red[4] + red[5] + red[6] + red[7];
    float mu = ts / (float)D_DIM;
    float var = t2 / (float)D_DIM - mu * mu;
    float rs = rsqrtf(var + EPS_LN);
    xn[l * D_DIM + tid]       = (__hip_bfloat16)((v0 - mu) * rs * w[tid] + b[tid]);
    xn[l * D_DIM + 256 + tid] = (__hip_bfloat16)((v1 - mu) * rs * w[256 + tid] + b[256 + tid]);
    xb[l * D_DIM + tid]       = (__hip_bfloat16)v0;
    xb[l * D_DIM + 256 + tid] = (__hip_bfloat16)v1;
}

// ---------------------------------------------------------------------------
// Transpose + fp32->bf16 convert.  Source in[R][C].
// MODE 0: out[c][r] = in[r][c]                          (plain)
// MODE 1: out[g(c)][r] = in[r][c], g(c)=(c&7)<<9|(c>>3) (vw column d/h swap)
// ---------------------------------------------------------------------------
template <int MODE>
__global__ __launch_bounds__(256) void tconv(const float* __restrict__ in,
                                             __hip_bfloat16* __restrict__ out,
                                             int R, int C) {
    __shared__ float t[32][33];
    int tx = threadIdx.x & 31, ti = threadIdx.x >> 5;
    int r0 = blockIdx.y * 32, c0 = blockIdx.x * 32;
#pragma unroll
    for (int ii = 0; ii < 4; ++ii)
        t[ti + ii * 8][tx] = in[(size_t)(r0 + ti + ii * 8) * C + c0 + tx];
    __syncthreads();
#pragma unroll
    for (int ii = 0; ii < 4; ++ii) {
        int c = c0 + ti + ii * 8;
        int orow = (MODE == 1) ? (((c & 7) << 9) | (c >> 3)) : c;
        out[(size_t)orow * R + r0 + tx] = (__hip_bfloat16)t[tx][ti + ii * 8];
    }
}

// ---------------------------------------------------------------------------
// bf16 MFMA GEMM: C[M][N] = A[M][K] @ Bt[N][K]^T  (+bias, epilogue)
// EPI: 0 exp(clip(+bias)) fp32 | 1 +bias(perm) fp32 | 2 relu(+bias) bf16
//      3 relu(+bias)+res fp32
// ---------------------------------------------------------------------------
template <int BM, int BN, int EPI, int PERM_BIAS, typename OUT_T>
__global__ __launch_bounds__(256) void gemm_mfma(const __hip_bfloat16* __restrict__ A,
                                                 const __hip_bfloat16* __restrict__ Bt,
                                                 const float* __restrict__ bias,
                                                 const float* __restrict__ res,
                                                 OUT_T* __restrict__ C,
                                                 int M, int N, int K) {
    constexpr int MT = BM / 32;
    constexpr int NT = BN / 32;
    __shared__ __align__(16) __hip_bfloat16 As[BM * 32];
    __shared__ __align__(16) __hip_bfloat16 Bs[BN * 32];
    const int tid = threadIdx.x;
    const int w = tid >> 6, lane = tid & 63;
    const int bm = blockIdx.y * BM, bn = blockIdx.x * BN;
    const int wm = (w >> 1) * (BM / 2), wn = (w & 1) * (BN / 2);
    const int quad = lane >> 4, l16 = lane & 15;
    const int srow = tid >> 2, scol = (tid & 3) * 8;
    constexpr int ALOADS = (BM * 32) / (256 * 8);
    constexpr int BLOADS = (BN * 32) / (256 * 8);

    floatx4 acc[MT][NT];
#pragma unroll
    for (int i = 0; i < MT; ++i)
#pragma unroll
        for (int j = 0; j < NT; ++j) acc[i][j] = (floatx4)0.f;

    for (int k0 = 0; k0 < K; k0 += 32) {
        __syncthreads();
#pragma unroll
        for (int j = 0; j < ALOADS; ++j)
            ASYNC_COPY16(A + (size_t)(bm + j * 64 + srow) * K + k0 + scol,
                         As + (j * 256 + w * 64) * 8);
#pragma unroll
        for (int j = 0; j < BLOADS; ++j)
            ASYNC_COPY16(Bt + (size_t)(bn + j * 64 + srow) * K + k0 + scol,
                         Bs + (j * 256 + w * 64) * 8);
        __syncthreads();
        short8 af[MT], bfr[NT];
#pragma unroll
        for (int mt = 0; mt < MT; ++mt)
            af[mt] = *(const short8*)(As + (wm + mt * 16 + l16) * 32 + quad * 8);
#pragma unroll
        for (int nt = 0; nt < NT; ++nt)
            bfr[nt] = *(const short8*)(Bs + (wn + nt * 16 + l16) * 32 + quad * 8);
#pragma unroll
        for (int mt = 0; mt < MT; ++mt)
#pragma unroll
            for (int nt = 0; nt < NT; ++nt)
                acc[mt][nt] = __builtin_amdgcn_mfma_f32_16x16x32_bf16(af[mt], bfr[nt],
                                                                      acc[mt][nt], 0, 0, 0);
    }
#pragma unroll
    for (int mt = 0; mt < MT; ++mt)
#pragma unroll
        for (int nt = 0; nt < NT; ++nt)
#pragma unroll
            for (int r = 0; r < 4; ++r) {
                int row = bm + wm + mt * 16 + quad * 4 + r;
                int col = bn + wn + nt * 16 + l16;
                float val = acc[mt][nt][r];
                int bi = PERM_BIAS ? (((col & 511) << 3) | (col >> 9)) : col;
                val += bias[bi];
                if (EPI == 0) val = expf(fminf(fmaxf(val, -10.f), 10.f));
                if (EPI == 2) val = fmaxf(val, 0.f);
                if (EPI == 3) val = fmaxf(val, 0.f) + res[(size_t)row * N + col];
                C[(size_t)row * N + col] = (OUT_T)val;
            }
}

// ---------------------------------------------------------------------------
// Pass A: per-chunk KV sums. v layout [l][h*D+d]. S[c][a][h][d].
// ---------------------------------------------------------------------------
__global__ __launch_bounds__(256) void passA_kernel(const float* __restrict__ k,
                                                    const float* __restrict__ v,
                                                    float* __restrict__ S) {
    int c = blockIdx.x, h = blockIdx.y, dg = blockIdx.z;
    int tid = threadIdx.x;
    int d = dg * 256 + tid;
    __shared__ float ks[CH][A_DIM];
    for (int e = tid; e < CH * A_DIM; e += 256) {
        int l = e >> 5, a = e & 31;
        ks[l][a] = k[(c * CH + l) * AH + a * H_DIM + h];
    }
    __syncthreads();
    float acc[A_DIM];
#pragma unroll
    for (int a = 0; a < A_DIM; ++a) acc[a] = 0.f;
    for (int l = 0; l < CH; ++l) {
        float vv = v[(size_t)(c * CH + l) * DH + h * D_DIM + d];
#pragma unroll
        for (int a = 0; a < A_DIM; ++a) acc[a] += ks[l][a] * vv;
    }
#pragma unroll
    for (int a = 0; a < A_DIM; ++a)
        S[(size_t)((c * A_DIM + a) * H_DIM + h) * D_DIM + d] = acc[a];
}

__global__ __launch_bounds__(256) void scanS_kernel(const float* __restrict__ S,
                                                    float* __restrict__ P) {
    int j = blockIdx.x * 256 + threadIdx.x;
    float run = 0.f;
    for (int c = 0; c < NC; ++c) {
        P[(size_t)c * (A_DIM * H_DIM * D_DIM) + j] = run;
        run += S[(size_t)c * (A_DIM * H_DIM * D_DIM) + j];
    }
}

__global__ __launch_bounds__(256) void passC_kernel(const float* __restrict__ q,
                                                    const float* __restrict__ k,
                                                    const float* __restrict__ v,
                                                    const float* __restrict__ P,
                                                    float* __restrict__ qkv) {
    int c = blockIdx.x, h = blockIdx.y, dg = blockIdx.z;
    int tid = threadIdx.x;
    int d = dg * 256 + tid;
    __shared__ float ks[CH][A_DIM];
    __shared__ float qs[CH][A_DIM];
    for (int e = tid; e < CH * A_DIM; e += 256) {
        int l = e >> 5, a = e & 31;
        int gi = (c * CH + l) * AH + a * H_DIM + h;
        ks[l][a] = k[gi];
        qs[l][a] = q[gi];
    }
    __syncthreads();
    float st[A_DIM];
#pragma unroll
    for (int a = 0; a < A_DIM; ++a)
        st[a] = P[(size_t)((c * A_DIM + a) * H_DIM + h) * D_DIM + d];
    for (int l = 0; l < CH; ++l) {
        float vv = v[(size_t)(c * CH + l) * DH + h * D_DIM + d];
        float s = 0.f;
#pragma unroll
        for (int a = 0; a < A_DIM; ++a) {
            st[a] += ks[l][a] * vv;
            s += qs[l][a] * st[a];
        }
        qkv[(size_t)(c * CH + l) * DH + h * D_DIM + d] = s;
    }
}

// ---------------------------------------------------------------------------
// den path
// ---------------------------------------------------------------------------
__global__ __launch_bounds__(256) void ka_kernel(const float* __restrict__ k, float* __restrict__ Ka) {
    int c = blockIdx.x, t = threadIdx.x;
    float s = 0.f;
    for (int l = 0; l < CH; ++l) s += k[(c * CH + l) * AH + t];
    Ka[c * AH + t] = s;
}

__global__ __launch_bounds__(256) void kp_kernel(const float* __restrict__ Ka, float* __restrict__ Kp) {
    int t = threadIdx.x;
    float run = 0.f;
    for (int c = 0; c < NC; ++c) {
        Kp[c * AH + t] = run;
        run += Ka[c * AH + t];
    }
}

__global__ __launch_bounds__(256) void kcum_kernel(const float* __restrict__ k,
                                                   const float* __restrict__ Kp,
                                                   float* __restrict__ kc) {
    int c = blockIdx.x, t = threadIdx.x;
    float run = Kp[c * AH + t];
    for (int l = 0; l < CH; ++l) {
        int gi = (c * CH + l) * AH + t;
        run += k[gi];
        kc[gi] = run;
    }
}

__global__ __launch_bounds__(256) void den_kernel(const float* __restrict__ q,
                                                  const float* __restrict__ kc,
                                                  float* __restrict__ den) {
    int idx = blockIdx.x * 256 + threadIdx.x;
    int l = idx >> 3, h = idx & 7;
    float s = 0.f;
#pragma unroll
    for (int a = 0; a < A_DIM; ++a)
        s += q[l * AH + a * H_DIM + h] * kc[l * AH + a * H_DIM + h];
    den[idx] = s;
}

// ---------------------------------------------------------------------------
// LN1 over (D,H) + broadcast residual. qkv layout [l][h*D+d] (scan layout);
// y written bf16 in plain [l][d*H+h] layout via LDS reorder.
// ---------------------------------------------------------------------------
__global__ __launch_bounds__(256) void ln1_kernel(const float* __restrict__ qkv,
                                                  const float* __restrict__ den,
                                                  const float* __restrict__ x,
                                                  const float* __restrict__ w,
                                                  const float* __restrict__ b,
                                                  __hip_bfloat16* __restrict__ y) {
    int l = blockIdx.x, tid = threadIdx.x;
    __shared__ float dsh[8];
    __shared__ float yl[DH];
    __shared__ float red[8];
    if (tid < 8) dsh[tid] = den[l * H_DIM + tid];
    __syncthreads();
    float t[16];
    float s = 0.f, s2 = 0.f;
#pragma unroll
    for (int j = 0; j < 16; ++j) {
        int e = j * 256 + tid;
        float val = qkv[(size_t)l * DH + e] / dsh[e >> 9];
        t[j] = val;
        s += val;
        s2 += val * val;
    }
    for (int off = 32; off > 0; off >>= 1) {
        s += __shfl_down(s, off);
        s2 += __shfl_down(s2, off);
    }
    int lane = tid & 63, wid = tid >> 6;
    if (lane == 0) { red[wid] = s; red[4 + wid] = s2; }
    __syncthreads();
    float ts = red[0] + red[1] + red[2] + red[3];
    float t2 = red[4] + red[5] + red[6] + red[7];
    float mu = ts / (float)DH;
    float var = t2 / (float)DH - mu * mu;
    float rs = rsqrtf(var + EPS_LN);
#pragma unroll
    for (int j = 0; j < 16; ++j) {
        int e = j * 256 + tid;
        int h = e >> 9, d = e & 511;
        int dh = d * H_DIM + h;
        yl[dh] = x[l * D_DIM + d] + (t[j] - mu) * rs * w[dh] + b[dh];
    }
    __syncthreads();
#pragma unroll
    for (int j = 0; j < 16; ++j) {
        int e = j * 256 + tid;
        y[(size_t)l * DH + e] = (__hip_bfloat16)yl[e];
    }
}

// ---------------------------------------------------------------------------
// Launch
// ---------------------------------------------------------------------------
extern "C" void kernel_launch(void* const* d_in, const int* in_sizes, int n_in,
                              void* d_out, int out_size, void* d_ws, size_t ws_size,
                              hipStream_t stream) {
    const float* x     = (const float*)d_in[0];
    const float* ln0_w = (const float*)d_in[1];
    const float* ln0_b = (const float*)d_in[2];
    const float* ln1_w = (const float*)d_in[3];
    const float* ln1_b = (const float*)d_in[4];
    const float* qw    = (const float*)d_in[5];
    const float* qb    = (const float*)d_in[6];
    const float* kw    = (const float*)d_in[7];
    const float* kb    = (const float*)d_in[8];
    const float* vw    = (const float*)d_in[9];
    const float* vb    = (const float*)d_in[10];
    const float* w1    = (const float*)d_in[11];
    const float* b1    = (const float*)d_in[12];
    const float* w2    = (const float*)d_in[13];
    const float* b2    = (const float*)d_in[14];
    float* out = (float*)d_out;

    char* ws = (char*)d_ws;
    __hip_bfloat16* xn_bf = (__hip_bfloat16*)(ws + 0);         // 1 MB
    __hip_bfloat16* xbf   = (__hip_bfloat16*)(ws + 1048576);   // 1 MB
    __hip_bfloat16* qwt   = (__hip_bfloat16*)(ws + 2097152);   // 0.25 MB
    __hip_bfloat16* kwt   = (__hip_bfloat16*)(ws + 2359296);   // 0.25 MB
    __hip_bfloat16* vwt   = (__hip_bfloat16*)(ws + 2621440);   // 4 MB
    __hip_bfloat16* w1t   = (__hip_bfloat16*)(ws + 6815744);   // 16 MB
    __hip_bfloat16* w2t   = (__hip_bfloat16*)(ws + 23592960);  // 2 MB
    float* q   = (float*)(ws + 25690112);                      // 1 MB
    float* k   = (float*)(ws + 26738688);                      // 1 MB
    float* v   = (float*)(ws + 27787264);                      // 16 MB
    float* S   = (float*)(ws + 44564480);                      // 8 MB
    float* P   = (float*)(ws + 52953088);                      // 8 MB
    float* qkv = (float*)(ws + 61341696);                      // 16 MB
    float* Ka  = (float*)(ws + 78118912);
    float* Kp  = (float*)(ws + 78135296);
    float* kc  = (float*)(ws + 78151680);                      // 1 MB
    float* den = (float*)(ws + 79200256);
    __hip_bfloat16* h1 = (__hip_bfloat16*)S;  // alias: S dead after scanS
    __hip_bfloat16* y  = (__hip_bfloat16*)P;  // alias: P dead after passC

    // LN0 + bf16 casts
    ln0_kernel<<<L_SEQ, 256, 0, stream>>>(x, ln0_w, ln0_b, xn_bf, xbf);
    // weight converts (transpose to [N][K] bf16)
    tconv<0><<<dim3(AH / 32, D_DIM / 32), 256, 0, stream>>>(qw, qwt, D_DIM, AH);
    tconv<0><<<dim3(AH / 32, D_DIM / 32), 256, 0, stream>>>(kw, kwt, D_DIM, AH);
    tconv<1><<<dim3(DH / 32, D_DIM / 32), 256, 0, stream>>>(vw, vwt, D_DIM, DH);
    tconv<0><<<dim3(F_DIM / 32, DH / 32), 256, 0, stream>>>(w1, w1t, DH, F_DIM);
    tconv<0><<<dim3(D_DIM / 32, F_DIM / 32), 256, 0, stream>>>(w2, w2t, F_DIM, D_DIM);
    // q/k/v projections
    gemm_mfma<64, 64, 0, 0, float><<<dim3(AH / 64, L_SEQ / 64), 256, 0, stream>>>(
        xn_bf, qwt, qb, nullptr, q, L_SEQ, AH, D_DIM);
    gemm_mfma<64, 64, 0, 0, float><<<dim3(AH / 64, L_SEQ / 64), 256, 0, stream>>>(
        xn_bf, kwt, kb, nullptr, k, L_SEQ, AH, D_DIM);
    gemm_mfma<128, 128, 1, 1, float><<<dim3(DH / 128, L_SEQ / 128), 256, 0, stream>>>(
        xbf, vwt, vb, nullptr, v, L_SEQ, DH, D_DIM);
    // chunked KV scan
    passA_kernel<<<dim3(NC, H_DIM, 2), 256, 0, stream>>>(k, v, S);
    scanS_kernel<<<(A_DIM * H_DIM * D_DIM) / 256, 256, 0, stream>>>(S, P);
    passC_kernel<<<dim3(NC, H_DIM, 2), 256, 0, stream>>>(q, k, v, P, qkv);
    // den path
    ka_kernel<<<NC, 256, 0, stream>>>(k, Ka);
    kp_kernel<<<1, 256, 0, stream>>>(Ka, Kp);
    kcum_kernel<<<NC, 256, 0, stream>>>(k, Kp, kc);
    den_kernel<<<(L_SEQ * H_DIM) / 256, 256, 0, stream>>>(q, kc, den);
    // LN1 + residual -> y (bf16)
    ln1_kernel<<<L_SEQ, 256, 0, stream>>>(qkv, den, x, ln1_w, ln1_b, y);
    // MLP
    gemm_mfma<64, 128, 2, 0, __hip_bfloat16><<<dim3(F_DIM / 128, L_SEQ / 64), 256, 0, stream>>>(
        y, w1t, b1, nullptr, h1, L_SEQ, F_DIM, DH);
    gemm_mfma<64, 64, 3, 0, float><<<dim3(D_DIM / 64, L_SEQ / 64), 256, 0, stream>>>(
        h1, w2t, b2, x, out, L_SEQ, D_DIM, F_DIM);

    (void)in_sizes; (void)n_in; (void)out_size; (void)ws_size;
}

// Round 3
// 283.288 us; speedup vs baseline: 2.3318x; 1.1932x over previous
//
#include <hip/hip_runtime.h>
#include <hip/hip_bf16.h>
#include <math.h>

#define L_SEQ 1024
#define D_DIM 512
#define A_DIM 32
#define H_DIM 8
#define F_DIM 2048
#define AH 256
#define DH 4096
#define NC 16
#define CH 64
#define QKN 512
#define EPS_LN 1e-5f

typedef __attribute__((ext_vector_type(8))) short short8;
typedef __attribute__((ext_vector_type(4))) float floatx4;

#define ASYNC_COPY16(gp, lp)                                                     \
    __builtin_amdgcn_global_load_lds(                                            \
        (const __attribute__((address_space(1))) void*)(const void*)(gp),        \
        (__attribute__((address_space(3))) void*)(void*)(lp), 16, 0, 0)

// ---------------------------------------------------------------------------
// LN0: per-row layernorm over D; writes bf16 xn and bf16 copy of x
// ---------------------------------------------------------------------------
__global__ __launch_bounds__(256) void ln0_kernel(const float* __restrict__ x,
                                                  const float* __restrict__ w,
                                                  const float* __restrict__ b,
                                                  __hip_bfloat16* __restrict__ xn,
                                                  __hip_bfloat16* __restrict__ xb) {
    int l = blockIdx.x;
    int tid = threadIdx.x;
    float v0 = x[l * D_DIM + tid];
    float v1 = x[l * D_DIM + 256 + tid];
    float s = v0 + v1, s2 = v0 * v0 + v1 * v1;
    for (int off = 32; off > 0; off >>= 1) {
        s += __shfl_down(s, off);
        s2 += __shfl_down(s2, off);
    }
    __shared__ float red[8];
    int lane = tid & 63, wid = tid >> 6;
    if (lane == 0) { red[wid] = s; red[4 + wid] = s2; }
    __syncthreads();
    float ts = red[0] + red[1] + red[2] + red[3];
    float t2 = red[4] + red[5] + red[6] + red[7];
    float mu = ts / (float)D_DIM;
    float var = t2 / (float)D_DIM - mu * mu;
    float rs = rsqrtf(var + EPS_LN);
    xn[l * D_DIM + tid]       = (__hip_bfloat16)((v0 - mu) * rs * w[tid] + b[tid]);
    xn[l * D_DIM + 256 + tid] = (__hip_bfloat16)((v1 - mu) * rs * w[256 + tid] + b[256 + tid]);
    xb[l * D_DIM + tid]       = (__hip_bfloat16)v0;
    xb[l * D_DIM + 256 + tid] = (__hip_bfloat16)v1;
}

// ---------------------------------------------------------------------------
// Transpose + fp32->bf16. in[R][C]; MODE0: out[c][r]; MODE1: out[g(c)][r],
// g(c) = (c&7)<<9 | c>>3  (vw d/h swap)
// ---------------------------------------------------------------------------
template <int MODE>
__global__ __launch_bounds__(256) void tconv(const float* __restrict__ in,
                                             __hip_bfloat16* __restrict__ out,
                                             int R, int C) {
    __shared__ float t[32][33];
    int tx = threadIdx.x & 31, ti = threadIdx.x >> 5;
    int r0 = blockIdx.y * 32, c0 = blockIdx.x * 32;
#pragma unroll
    for (int ii = 0; ii < 4; ++ii)
        t[ti + ii * 8][tx] = in[(size_t)(r0 + ti + ii * 8) * C + c0 + tx];
    __syncthreads();
#pragma unroll
    for (int ii = 0; ii < 4; ++ii) {
        int c = c0 + ti + ii * 8;
        int orow = (MODE == 1) ? (((c & 7) << 9) | (c >> 3)) : c;
        out[(size_t)orow * R + r0 + tx] = (__hip_bfloat16)t[tx][ti + ii * 8];
    }
}

// ---------------------------------------------------------------------------
// 64x64 tile, BK=64, XOR-swizzled LDS. C = A[M,K] @ Bt[N,K]^T.
// EPI 0: qk exp(clip(+bias|bias2)) -> fp32
// EPI 1: v  +bias(perm)            -> bf16
// EPI 2: h1 relu(+bias)            -> bf16
// EPI 4: raw split-K partial       -> fp32 at Cv + kz*M*N
// ---------------------------------------------------------------------------
template <int EPI>
__global__ __launch_bounds__(256) void gemm64(const __hip_bfloat16* __restrict__ A,
                                              const __hip_bfloat16* __restrict__ Bt,
                                              const float* __restrict__ bias,
                                              const float* __restrict__ bias2,
                                              void* __restrict__ Cv,
                                              int M, int N, int K, int Ksub) {
    __shared__ __align__(16) __hip_bfloat16 As[64 * 64];
    __shared__ __align__(16) __hip_bfloat16 Bs[64 * 64];
    const int tid = threadIdx.x;
    const int w = tid >> 6, lane = tid & 63;
    const int bm = blockIdx.y * 64, bn = blockIdx.x * 64;
    const int kz = blockIdx.z;
    const int wm = (w >> 1) * 32, wn = (w & 1) * 32;
    const int quad = lane >> 4, l16 = lane & 15;
    const int srow_base = w * 8 + (lane >> 3);
    const int c7 = lane & 7;

    floatx4 acc[2][2];
#pragma unroll
    for (int i = 0; i < 2; ++i)
#pragma unroll
        for (int j = 0; j < 2; ++j) acc[i][j] = (floatx4)0.f;

    const int k_beg = kz * Ksub, k_end = k_beg + Ksub;
    for (int k0 = k_beg; k0 < k_end; k0 += 64) {
        __syncthreads();
#pragma unroll
        for (int j = 0; j < 2; ++j) {
            int row = j * 32 + srow_base;
            int cg = c7 ^ (row & 7);
            ASYNC_COPY16(A + (size_t)(bm + row) * K + k0 + cg * 8,
                         As + (j * 256 + w * 64) * 8);
            ASYNC_COPY16(Bt + (size_t)(bn + row) * K + k0 + cg * 8,
                         Bs + (j * 256 + w * 64) * 8);
        }
        __syncthreads();
        short8 af[2][2], bfr[2][2];
#pragma unroll
        for (int mt = 0; mt < 2; ++mt) {
            int r = wm + mt * 16 + l16;
            int x0 = r * 64, sw = r & 7;
            af[mt][0] = *(const short8*)(As + x0 + ((0 + quad) ^ sw) * 8);
            af[mt][1] = *(const short8*)(As + x0 + ((4 + quad) ^ sw) * 8);
        }
#pragma unroll
        for (int nt = 0; nt < 2; ++nt) {
            int r = wn + nt * 16 + l16;
            int x0 = r * 64, sw = r & 7;
            bfr[nt][0] = *(const short8*)(Bs + x0 + ((0 + quad) ^ sw) * 8);
            bfr[nt][1] = *(const short8*)(Bs + x0 + ((4 + quad) ^ sw) * 8);
        }
#pragma unroll
        for (int ks = 0; ks < 2; ++ks)
#pragma unroll
            for (int mt = 0; mt < 2; ++mt)
#pragma unroll
                for (int nt = 0; nt < 2; ++nt)
                    acc[mt][nt] = __builtin_amdgcn_mfma_f32_16x16x32_bf16(
                        af[mt][ks], bfr[nt][ks], acc[mt][nt], 0, 0, 0);
    }
#pragma unroll
    for (int mt = 0; mt < 2; ++mt)
#pragma unroll
        for (int nt = 0; nt < 2; ++nt)
#pragma unroll
            for (int r = 0; r < 4; ++r) {
                int row = bm + wm + mt * 16 + quad * 4 + r;
                int col = bn + wn + nt * 16 + l16;
                float val = acc[mt][nt][r];
                if (EPI == 0) {
                    float bb = (col < 256) ? bias[col] : bias2[col - 256];
                    val = expf(fminf(fmaxf(val + bb, -10.f), 10.f));
                    ((float*)Cv)[(size_t)row * N + col] = val;
                } else if (EPI == 1) {
                    int bi = ((col & 511) << 3) | (col >> 9);
                    ((__hip_bfloat16*)Cv)[(size_t)row * N + col] =
                        (__hip_bfloat16)(val + bias[bi]);
                } else if (EPI == 2) {
                    ((__hip_bfloat16*)Cv)[(size_t)row * N + col] =
                        (__hip_bfloat16)fmaxf(val + bias[col], 0.f);
                } else {
                    ((float*)Cv)[((size_t)kz * M + row) * N + col] = val;
                }
            }
}

// ---------------------------------------------------------------------------
// Split-K reduce for w2: out = relu(sum_kz partial + b2) + x
// ---------------------------------------------------------------------------
__global__ __launch_bounds__(256) void w2red(const float* __restrict__ part,
                                             const float* __restrict__ b2,
                                             const float* __restrict__ x,
                                             float* __restrict__ out) {
    size_t e = ((size_t)blockIdx.x * 256 + threadIdx.x) * 4;
    const size_t MN = (size_t)L_SEQ * D_DIM;
    float4 v0 = *(const float4*)(part + e);
    float4 v1 = *(const float4*)(part + MN + e);
    float4 v2 = *(const float4*)(part + 2 * MN + e);
    float4 v3 = *(const float4*)(part + 3 * MN + e);
    float4 bb = *(const float4*)(b2 + (e & 511));
    float4 xx = *(const float4*)(x + e);
    float4 r;
    r.x = fmaxf(v0.x + v1.x + v2.x + v3.x + bb.x, 0.f) + xx.x;
    r.y = fmaxf(v0.y + v1.y + v2.y + v3.y + bb.y, 0.f) + xx.y;
    r.z = fmaxf(v0.z + v1.z + v2.z + v3.z + bb.z, 0.f) + xx.z;
    r.w = fmaxf(v0.w + v1.w + v2.w + v3.w + bb.w, 0.f) + xx.w;
    *(float4*)(out + e) = r;
}

// ---------------------------------------------------------------------------
// Pass A: per-chunk KV sums. k cols 256.. of qk. v bf16 [l][h*D+d].
// ---------------------------------------------------------------------------
__global__ __launch_bounds__(256) void passA_kernel(const float* __restrict__ qk,
                                                    const __hip_bfloat16* __restrict__ v,
                                                    float* __restrict__ S) {
    int c = blockIdx.x, h = blockIdx.y, dg = blockIdx.z;
    int tid = threadIdx.x;
    int d = dg * 256 + tid;
    __shared__ float ks[CH][A_DIM];
    for (int e = tid; e < CH * A_DIM; e += 256) {
        int l = e >> 5, a = e & 31;
        ks[l][a] = qk[(c * CH + l) * QKN + 256 + a * H_DIM + h];
    }
    __syncthreads();
    float acc[A_DIM];
#pragma unroll
    for (int a = 0; a < A_DIM; ++a) acc[a] = 0.f;
    for (int l = 0; l < CH; ++l) {
        float vv = (float)v[(size_t)(c * CH + l) * DH + h * D_DIM + d];
#pragma unroll
        for (int a = 0; a < A_DIM; ++a) acc[a] += ks[l][a] * vv;
    }
#pragma unroll
    for (int a = 0; a < A_DIM; ++a)
        S[(size_t)((c * A_DIM + a) * H_DIM + h) * D_DIM + d] = acc[a];
}

__global__ __launch_bounds__(256) void scanS_kernel(const float* __restrict__ S,
                                                    float* __restrict__ P) {
    int j = blockIdx.x * 256 + threadIdx.x;
    float run = 0.f;
    for (int c = 0; c < NC; ++c) {
        P[(size_t)c * (A_DIM * H_DIM * D_DIM) + j] = run;
        run += S[(size_t)c * (A_DIM * H_DIM * D_DIM) + j];
    }
}

__global__ __launch_bounds__(256) void passC_kernel(const float* __restrict__ qk,
                                                    const __hip_bfloat16* __restrict__ v,
                                                    const float* __restrict__ P,
                                                    __hip_bfloat16* __restrict__ qkv) {
    int c = blockIdx.x, h = blockIdx.y, dg = blockIdx.z;
    int tid = threadIdx.x;
    int d = dg * 256 + tid;
    __shared__ float ks[CH][A_DIM];
    __shared__ float qs[CH][A_DIM];
    for (int e = tid; e < CH * A_DIM; e += 256) {
        int l = e >> 5, a = e & 31;
        int gi = (c * CH + l) * QKN + a * H_DIM + h;
        qs[l][a] = qk[gi];
        ks[l][a] = qk[gi + 256];
    }
    __syncthreads();
    float st[A_DIM];
#pragma unroll
    for (int a = 0; a < A_DIM; ++a)
        st[a] = P[(size_t)((c * A_DIM + a) * H_DIM + h) * D_DIM + d];
    for (int l = 0; l < CH; ++l) {
        float vv = (float)v[(size_t)(c * CH + l) * DH + h * D_DIM + d];
        float s = 0.f;
#pragma unroll
        for (int a = 0; a < A_DIM; ++a) {
            st[a] += ks[l][a] * vv;
            s += qs[l][a] * st[a];
        }
        qkv[(size_t)(c * CH + l) * DH + h * D_DIM + d] = (__hip_bfloat16)s;
    }
}

// ---------------------------------------------------------------------------
// den path: chunk sums of k, then merged prefix+cumsum+dot
// ---------------------------------------------------------------------------
__global__ __launch_bounds__(256) void ka_kernel(const float* __restrict__ qk,
                                                 float* __restrict__ Ka) {
    int c = blockIdx.x, t = threadIdx.x;
    float s = 0.f;
    for (int l = 0; l < CH; ++l) s += qk[(c * CH + l) * QKN + 256 + t];
    Ka[c * AH + t] = s;
}

__global__ __launch_bounds__(256) void den2_kernel(const float* __restrict__ qk,
                                                   const float* __restrict__ Ka,
                                                   float* __restrict__ den) {
    int c = blockIdx.x, half = blockIdx.y, t = threadIdx.x;
    __shared__ float part[32][257];
    float run = 0.f;
    for (int cc = 0; cc < c; ++cc) run += Ka[cc * AH + t];
    int lbase = c * CH + half * 32;
    for (int l = c * CH; l < lbase; ++l) run += qk[l * QKN + 256 + t];
    for (int j = 0; j < 32; ++j) {
        int l = lbase + j;
        run += qk[l * QKN + 256 + t];
        part[j][t] = qk[l * QKN + t] * run;
    }
    __syncthreads();
    int l = t >> 3, h = t & 7;
    float s = 0.f;
#pragma unroll
    for (int a = 0; a < A_DIM; ++a) s += part[l][a * H_DIM + h];
    den[(lbase + l) * H_DIM + h] = s;
}

// ---------------------------------------------------------------------------
// LN1 over (D,H) + residual. qkv bf16 [l][h*D+d]; y bf16 [l][d*H+h].
// ---------------------------------------------------------------------------
__global__ __launch_bounds__(256) void ln1_kernel(const __hip_bfloat16* __restrict__ qkv,
                                                  const float* __restrict__ den,
                                                  const float* __restrict__ x,
                                                  const float* __restrict__ w,
                                                  const float* __restrict__ b,
                                                  __hip_bfloat16* __restrict__ y) {
    int l = blockIdx.x, tid = threadIdx.x;
    __shared__ float dsh[8];
    __shared__ float yl[DH];
    __shared__ float red[8];
    if (tid < 8) dsh[tid] = den[l * H_DIM + tid];
    __syncthreads();
    float t[16];
    float s = 0.f, s2 = 0.f;
#pragma unroll
    for (int j = 0; j < 16; ++j) {
        int e = j * 256 + tid;
        float val = (float)qkv[(size_t)l * DH + e] / dsh[e >> 9];
        t[j] = val;
        s += val;
        s2 += val * val;
    }
    for (int off = 32; off > 0; off >>= 1) {
        s += __shfl_down(s, off);
        s2 += __shfl_down(s2, off);
    }
    int lane = tid & 63, wid = tid >> 6;
    if (lane == 0) { red[wid] = s; red[4 + wid] = s2; }
    __syncthreads();
    float ts = red[0] + red[1] + red[2] + red[3];
    float t2 = red[4] + red[5] + red[6] + red[7];
    float mu = ts / (float)DH;
    float var = t2 / (float)DH - mu * mu;
    float rs = rsqrtf(var + EPS_LN);
#pragma unroll
    for (int j = 0; j < 16; ++j) {
        int e = j * 256 + tid;
        int h = e >> 9, d = e & 511;
        int dh = d * H_DIM + h;
        yl[dh] = x[l * D_DIM + d] + (t[j] - mu) * rs * w[dh] + b[dh];
    }
    __syncthreads();
#pragma unroll
    for (int j = 0; j < 16; ++j) {
        int e = j * 256 + tid;
        y[(size_t)l * DH + e] = (__hip_bfloat16)yl[e];
    }
}

// ---------------------------------------------------------------------------
// Launch
// ---------------------------------------------------------------------------
extern "C" void kernel_launch(void* const* d_in, const int* in_sizes, int n_in,
                              void* d_out, int out_size, void* d_ws, size_t ws_size,
                              hipStream_t stream) {
    const float* x     = (const float*)d_in[0];
    const float* ln0_w = (const float*)d_in[1];
    const float* ln0_b = (const float*)d_in[2];
    const float* ln1_w = (const float*)d_in[3];
    const float* ln1_b = (const float*)d_in[4];
    const float* qw    = (const float*)d_in[5];
    const float* qb    = (const float*)d_in[6];
    const float* kw    = (const float*)d_in[7];
    const float* kb    = (const float*)d_in[8];
    const float* vw    = (const float*)d_in[9];
    const float* vb    = (const float*)d_in[10];
    const float* w1    = (const float*)d_in[11];
    const float* b1    = (const float*)d_in[12];
    const float* w2    = (const float*)d_in[13];
    const float* b2    = (const float*)d_in[14];
    float* out = (float*)d_out;

    char* ws = (char*)d_ws;
    __hip_bfloat16* xn_bf = (__hip_bfloat16*)(ws + 0);         // 1 MB
    __hip_bfloat16* xbf   = (__hip_bfloat16*)(ws + 1048576);   // 1 MB
    __hip_bfloat16* qkwt  = (__hip_bfloat16*)(ws + 2097152);   // 0.5 MB
    __hip_bfloat16* vwt   = (__hip_bfloat16*)(ws + 2621440);   // 4 MB
    __hip_bfloat16* w1t   = (__hip_bfloat16*)(ws + 6815744);   // 16 MB
    __hip_bfloat16* w2t   = (__hip_bfloat16*)(ws + 23592960);  // 2 MB
    float* qk  = (float*)(ws + 25690112);                      // 2 MB
    __hip_bfloat16* vb16 = (__hip_bfloat16*)(ws + 27787264);   // 8 MB
    float* S   = (float*)(ws + 36175872);                      // 8 MB
    float* P   = (float*)(ws + 44564480);                      // 8 MB
    __hip_bfloat16* qkvb = (__hip_bfloat16*)(ws + 52953088);   // 8 MB
    float* Ka  = (float*)(ws + 61341696);                      // 16 KB
    float* den = (float*)(ws + 61358080);                      // 32 KB
    __hip_bfloat16* y  = (__hip_bfloat16*)P;     // alias: P dead after passC
    __hip_bfloat16* h1 = (__hip_bfloat16*)S;     // alias: S dead after scanS
    float* w2part = (float*)qkvb;                // alias: qkv dead after ln1

    ln0_kernel<<<L_SEQ, 256, 0, stream>>>(x, ln0_w, ln0_b, xn_bf, xbf);
    tconv<0><<<dim3(AH / 32, D_DIM / 32), 256, 0, stream>>>(qw, qkwt, D_DIM, AH);
    tconv<0><<<dim3(AH / 32, D_DIM / 32), 256, 0, stream>>>(kw, qkwt + (size_t)AH * D_DIM, D_DIM, AH);
    tconv<1><<<dim3(DH / 32, D_DIM / 32), 256, 0, stream>>>(vw, vwt, D_DIM, DH);
    tconv<0><<<dim3(F_DIM / 32, DH / 32), 256, 0, stream>>>(w1, w1t, DH, F_DIM);
    tconv<0><<<dim3(D_DIM / 32, F_DIM / 32), 256, 0, stream>>>(w2, w2t, F_DIM, D_DIM);
    // fused q|k projection -> qk [L][512] fp32
    gemm64<0><<<dim3(QKN / 64, L_SEQ / 64, 1), 256, 0, stream>>>(
        xn_bf, qkwt, qb, kb, qk, L_SEQ, QKN, D_DIM, D_DIM);
    // v projection -> bf16 [L][h*D+d]
    gemm64<1><<<dim3(DH / 64, L_SEQ / 64, 1), 256, 0, stream>>>(
        xbf, vwt, vb, nullptr, vb16, L_SEQ, DH, D_DIM, D_DIM);
    // chunked KV scan
    passA_kernel<<<dim3(NC, H_DIM, 2), 256, 0, stream>>>(qk, vb16, S);
    scanS_kernel<<<(A_DIM * H_DIM * D_DIM) / 256, 256, 0, stream>>>(S, P);
    passC_kernel<<<dim3(NC, H_DIM, 2), 256, 0, stream>>>(qk, vb16, P, qkvb);
    // den path
    ka_kernel<<<NC, 256, 0, stream>>>(qk, Ka);
    den2_kernel<<<dim3(NC, 2), 256, 0, stream>>>(qk, Ka, den);
    // LN1 + residual -> y bf16
    ln1_kernel<<<L_SEQ, 256, 0, stream>>>(qkvb, den, x, ln1_w, ln1_b, y);
    // MLP
    gemm64<2><<<dim3(F_DIM / 64, L_SEQ / 64, 1), 256, 0, stream>>>(
        y, w1t, b1, nullptr, h1, L_SEQ, F_DIM, DH, DH);
    gemm64<4><<<dim3(D_DIM / 64, L_SEQ / 64, 4), 256, 0, stream>>>(
        h1, w2t, nullptr, nullptr, w2part, L_SEQ, D_DIM, F_DIM, F_DIM / 4);
    w2red<<<(L_SEQ * D_DIM) / 1024, 256, 0, stream>>>(w2part, b2, x, out);

    (void)in_sizes; (void)n_in; (void)out_size; (void)ws_size;
}

// Round 4
// 262.445 us; speedup vs baseline: 2.5170x; 1.0794x over previous
//
#include <hip/hip_runtime.h>
#include <hip/hip_bf16.h>
#include <math.h>

#define L_SEQ 1024
#define D_DIM 512
#define A_DIM 32
#define H_DIM 8
#define F_DIM 2048
#define AH 256
#define DH 4096
#define NC 16
#define CH 64
#define QKN 512
#define EPS_LN 1e-5f

typedef __attribute__((ext_vector_type(8))) short short8;
typedef __attribute__((ext_vector_type(4))) float floatx4;

#define ASYNC_COPY16(gp, lp)                                                     \
    __builtin_amdgcn_global_load_lds(                                            \
        (const __attribute__((address_space(1))) void*)(const void*)(gp),        \
        (__attribute__((address_space(3))) void*)(void*)(lp), 16, 0, 0)

// ---------------------------------------------------------------------------
// prep: fused LN0 (+bf16 casts of x) and all weight transpose/converts.
// blocks [0,1024) ln0 rows; rest 32x32 tconv tiles per weight.
// ---------------------------------------------------------------------------
__global__ __launch_bounds__(256) void prep_kernel(const float* __restrict__ x,
                                                   const float* __restrict__ ln0w,
                                                   const float* __restrict__ ln0b,
                                                   const float* __restrict__ qw,
                                                   const float* __restrict__ kw,
                                                   const float* __restrict__ vw,
                                                   const float* __restrict__ w1,
                                                   const float* __restrict__ w2,
                                                   __hip_bfloat16* __restrict__ xn,
                                                   __hip_bfloat16* __restrict__ xb,
                                                   __hip_bfloat16* __restrict__ qkwt,
                                                   __hip_bfloat16* __restrict__ vwt,
                                                   __hip_bfloat16* __restrict__ w1t,
                                                   __hip_bfloat16* __restrict__ w2t) {
    __shared__ float tt[32][33];
    __shared__ float red[8];
    int bid = blockIdx.x;
    int tid = threadIdx.x;
    if (bid < 1024) {
        // ln0 row
        int l = bid;
        float v0 = x[l * D_DIM + tid];
        float v1 = x[l * D_DIM + 256 + tid];
        float s = v0 + v1, s2 = v0 * v0 + v1 * v1;
        for (int off = 32; off > 0; off >>= 1) {
            s += __shfl_down(s, off);
            s2 += __shfl_down(s2, off);
        }
        int lane = tid & 63, wid = tid >> 6;
        if (lane == 0) { red[wid] = s; red[4 + wid] = s2; }
        __syncthreads();
        float ts = red[0] + red[1] + red[2] + red[3];
        float t2 = red[4] + red[5] + red[6] + red[7];
        float mu = ts / (float)D_DIM;
        float var = t2 / (float)D_DIM - mu * mu;
        float rs = rsqrtf(var + EPS_LN);
        xn[l * D_DIM + tid]       = (__hip_bfloat16)((v0 - mu) * rs * ln0w[tid] + ln0b[tid]);
        xn[l * D_DIM + 256 + tid] = (__hip_bfloat16)((v1 - mu) * rs * ln0w[256 + tid] + ln0b[256 + tid]);
        xb[l * D_DIM + tid]       = (__hip_bfloat16)v0;
        xb[l * D_DIM + 256 + tid] = (__hip_bfloat16)v1;
        return;
    }
    const float* in;
    __hip_bfloat16* out;
    int R, C, mode = 0, t;
    if (bid < 1152)      { t = bid - 1024;  in = qw; out = qkwt;                         R = 512;  C = 256; }
    else if (bid < 1280) { t = bid - 1152;  in = kw; out = qkwt + (size_t)AH * D_DIM;    R = 512;  C = 256; }
    else if (bid < 3328) { t = bid - 1280;  in = vw; out = vwt;  mode = 1;               R = 512;  C = 4096; }
    else if (bid < 11520){ t = bid - 3328;  in = w1; out = w1t;                          R = 4096; C = 2048; }
    else                 { t = bid - 11520; in = w2; out = w2t;                          R = 2048; C = 512; }
    int ctiles = C >> 5;
    int cx = t % ctiles, cy = t / ctiles;
    int tx = tid & 31, ti = tid >> 5;
    int r0 = cy * 32, c0 = cx * 32;
#pragma unroll
    for (int ii = 0; ii < 4; ++ii)
        tt[ti + ii * 8][tx] = in[(size_t)(r0 + ti + ii * 8) * C + c0 + tx];
    __syncthreads();
#pragma unroll
    for (int ii = 0; ii < 4; ++ii) {
        int c = c0 + ti + ii * 8;
        int orow = mode ? (((c & 7) << 9) | (c >> 3)) : c;
        out[(size_t)orow * R + r0 + tx] = (__hip_bfloat16)tt[tx][ti + ii * 8];
    }
}

// ---------------------------------------------------------------------------
// 64x64 tile, BK=64, XOR-swizzled LDS. C = A[M,K] @ Bt[N,K]^T.
// STRIP>0: XCD-aware 1D-grid swizzle — xcd=bid&7 owns N-strip of STRIP tiles.
// EPI 0: qk exp(clip(+bias|bias2)) -> fp32
// EPI 1: v  +bias(perm)            -> bf16
// EPI 4: raw split-K partial       -> fp32 at Cv + kz*M*N
// ---------------------------------------------------------------------------
template <int EPI, int STRIP>
__global__ __launch_bounds__(256) void gemm64(const __hip_bfloat16* __restrict__ A,
                                              const __hip_bfloat16* __restrict__ Bt,
                                              const float* __restrict__ bias,
                                              const float* __restrict__ bias2,
                                              void* __restrict__ Cv,
                                              int M, int N, int K, int Ksub) {
    __shared__ __align__(16) __hip_bfloat16 As[64 * 64];
    __shared__ __align__(16) __hip_bfloat16 Bs[64 * 64];
    const int tid = threadIdx.x;
    const int w = tid >> 6, lane = tid & 63;
    int bx, by;
    if (STRIP > 0) {
        int bid = blockIdx.x;
        int r = bid >> 3;
        bx = (bid & 7) * STRIP + (r % STRIP);
        by = r / STRIP;
    } else {
        bx = blockIdx.x;
        by = blockIdx.y;
    }
    const int bm = by * 64, bn = bx * 64;
    const int kz = blockIdx.z;
    const int wm = (w >> 1) * 32, wn = (w & 1) * 32;
    const int quad = lane >> 4, l16 = lane & 15;
    const int srow_base = w * 8 + (lane >> 3);
    const int c7 = lane & 7;

    floatx4 acc[2][2];
#pragma unroll
    for (int i = 0; i < 2; ++i)
#pragma unroll
        for (int j = 0; j < 2; ++j) acc[i][j] = (floatx4)0.f;

    const int k_beg = kz * Ksub, k_end = k_beg + Ksub;
    for (int k0 = k_beg; k0 < k_end; k0 += 64) {
        __syncthreads();
#pragma unroll
        for (int j = 0; j < 2; ++j) {
            int row = j * 32 + srow_base;
            int cg = c7 ^ (row & 7);
            ASYNC_COPY16(A + (size_t)(bm + row) * K + k0 + cg * 8,
                         As + (j * 256 + w * 64) * 8);
            ASYNC_COPY16(Bt + (size_t)(bn + row) * K + k0 + cg * 8,
                         Bs + (j * 256 + w * 64) * 8);
        }
        __syncthreads();
        short8 af[2][2], bfr[2][2];
#pragma unroll
        for (int mt = 0; mt < 2; ++mt) {
            int r = wm + mt * 16 + l16;
            int x0 = r * 64, sw = r & 7;
            af[mt][0] = *(const short8*)(As + x0 + ((0 + quad) ^ sw) * 8);
            af[mt][1] = *(const short8*)(As + x0 + ((4 + quad) ^ sw) * 8);
        }
#pragma unroll
        for (int nt = 0; nt < 2; ++nt) {
            int r = wn + nt * 16 + l16;
            int x0 = r * 64, sw = r & 7;
            bfr[nt][0] = *(const short8*)(Bs + x0 + ((0 + quad) ^ sw) * 8);
            bfr[nt][1] = *(const short8*)(Bs + x0 + ((4 + quad) ^ sw) * 8);
        }
#pragma unroll
        for (int ks = 0; ks < 2; ++ks)
#pragma unroll
            for (int mt = 0; mt < 2; ++mt)
#pragma unroll
                for (int nt = 0; nt < 2; ++nt)
                    acc[mt][nt] = __builtin_amdgcn_mfma_f32_16x16x32_bf16(
                        af[mt][ks], bfr[nt][ks], acc[mt][nt], 0, 0, 0);
    }
#pragma unroll
    for (int mt = 0; mt < 2; ++mt)
#pragma unroll
        for (int nt = 0; nt < 2; ++nt)
#pragma unroll
            for (int r = 0; r < 4; ++r) {
                int row = bm + wm + mt * 16 + quad * 4 + r;
                int col = bn + wn + nt * 16 + l16;
                float val = acc[mt][nt][r];
                if (EPI == 0) {
                    float bb = (col < 256) ? bias[col] : bias2[col - 256];
                    val = expf(fminf(fmaxf(val + bb, -10.f), 10.f));
                    ((float*)Cv)[(size_t)row * N + col] = val;
                } else if (EPI == 1) {
                    int bi = ((col & 511) << 3) | (col >> 9);
                    ((__hip_bfloat16*)Cv)[(size_t)row * N + col] =
                        (__hip_bfloat16)(val + bias[bi]);
                } else {
                    ((float*)Cv)[((size_t)kz * M + row) * N + col] = val;
                }
            }
}

// ---------------------------------------------------------------------------
// Split-K=2 reduce for w1: h1 = bf16(relu(p0+p1+b1))
// ---------------------------------------------------------------------------
__global__ __launch_bounds__(256) void w1red(const float* __restrict__ part,
                                             const float* __restrict__ b1,
                                             __hip_bfloat16* __restrict__ h1) {
    size_t e = ((size_t)blockIdx.x * 256 + threadIdx.x) * 4;
    const size_t MN = (size_t)L_SEQ * F_DIM;
    float4 p0 = *(const float4*)(part + e);
    float4 p1 = *(const float4*)(part + MN + e);
    float4 bb = *(const float4*)(b1 + (e & (F_DIM - 1)));
    h1[e + 0] = (__hip_bfloat16)fmaxf(p0.x + p1.x + bb.x, 0.f);
    h1[e + 1] = (__hip_bfloat16)fmaxf(p0.y + p1.y + bb.y, 0.f);
    h1[e + 2] = (__hip_bfloat16)fmaxf(p0.z + p1.z + bb.z, 0.f);
    h1[e + 3] = (__hip_bfloat16)fmaxf(p0.w + p1.w + bb.w, 0.f);
}

// ---------------------------------------------------------------------------
// Split-K=4 reduce for w2: out = relu(sum partial + b2) + x
// ---------------------------------------------------------------------------
__global__ __launch_bounds__(256) void w2red(const float* __restrict__ part,
                                             const float* __restrict__ b2,
                                             const float* __restrict__ x,
                                             float* __restrict__ out) {
    size_t e = ((size_t)blockIdx.x * 256 + threadIdx.x) * 4;
    const size_t MN = (size_t)L_SEQ * D_DIM;
    float4 v0 = *(const float4*)(part + e);
    float4 v1 = *(const float4*)(part + MN + e);
    float4 v2 = *(const float4*)(part + 2 * MN + e);
    float4 v3 = *(const float4*)(part + 3 * MN + e);
    float4 bb = *(const float4*)(b2 + (e & 511));
    float4 xx = *(const float4*)(x + e);
    float4 r;
    r.x = fmaxf(v0.x + v1.x + v2.x + v3.x + bb.x, 0.f) + xx.x;
    r.y = fmaxf(v0.y + v1.y + v2.y + v3.y + bb.y, 0.f) + xx.y;
    r.z = fmaxf(v0.z + v1.z + v2.z + v3.z + bb.z, 0.f) + xx.z;
    r.w = fmaxf(v0.w + v1.w + v2.w + v3.w + bb.w, 0.f) + xx.w;
    *(float4*)(out + e) = r;
}

// ---------------------------------------------------------------------------
// Pass A: per-chunk KV sums. k cols 256.. of qk. v bf16 [l][h*D+d].
// ---------------------------------------------------------------------------
__global__ __launch_bounds__(256) void passA_kernel(const float* __restrict__ qk,
                                                    const __hip_bfloat16* __restrict__ v,
                                                    float* __restrict__ S) {
    int c = blockIdx.x, h = blockIdx.y, dg = blockIdx.z;
    int tid = threadIdx.x;
    int d = dg * 256 + tid;
    __shared__ float ks[CH][A_DIM];
    for (int e = tid; e < CH * A_DIM; e += 256) {
        int l = e >> 5, a = e & 31;
        ks[l][a] = qk[(c * CH + l) * QKN + 256 + a * H_DIM + h];
    }
    __syncthreads();
    float acc[A_DIM];
#pragma unroll
    for (int a = 0; a < A_DIM; ++a) acc[a] = 0.f;
    for (int l = 0; l < CH; ++l) {
        float vv = (float)v[(size_t)(c * CH + l) * DH + h * D_DIM + d];
#pragma unroll
        for (int a = 0; a < A_DIM; ++a) acc[a] += ks[l][a] * vv;
    }
#pragma unroll
    for (int a = 0; a < A_DIM; ++a)
        S[(size_t)((c * A_DIM + a) * H_DIM + h) * D_DIM + d] = acc[a];
}

__global__ __launch_bounds__(256) void scanS_kernel(const float* __restrict__ S,
                                                    float* __restrict__ P) {
    int j = blockIdx.x * 256 + threadIdx.x;
    float run = 0.f;
    for (int c = 0; c < NC; ++c) {
        P[(size_t)c * (A_DIM * H_DIM * D_DIM) + j] = run;
        run += S[(size_t)c * (A_DIM * H_DIM * D_DIM) + j];
    }
}

__global__ __launch_bounds__(256) void passC_kernel(const float* __restrict__ qk,
                                                    const __hip_bfloat16* __restrict__ v,
                                                    const float* __restrict__ P,
                                                    __hip_bfloat16* __restrict__ qkv) {
    int c = blockIdx.x, h = blockIdx.y, dg = blockIdx.z;
    int tid = threadIdx.x;
    int d = dg * 256 + tid;
    __shared__ float ks[CH][A_DIM];
    __shared__ float qs[CH][A_DIM];
    for (int e = tid; e < CH * A_DIM; e += 256) {
        int l = e >> 5, a = e & 31;
        int gi = (c * CH + l) * QKN + a * H_DIM + h;
        qs[l][a] = qk[gi];
        ks[l][a] = qk[gi + 256];
    }
    __syncthreads();
    float st[A_DIM];
#pragma unroll
    for (int a = 0; a < A_DIM; ++a)
        st[a] = P[(size_t)((c * A_DIM + a) * H_DIM + h) * D_DIM + d];
    for (int l = 0; l < CH; ++l) {
        float vv = (float)v[(size_t)(c * CH + l) * DH + h * D_DIM + d];
        float s = 0.f;
#pragma unroll
        for (int a = 0; a < A_DIM; ++a) {
            st[a] += ks[l][a] * vv;
            s += qs[l][a] * st[a];
        }
        qkv[(size_t)(c * CH + l) * DH + h * D_DIM + d] = (__hip_bfloat16)s;
    }
}

// ---------------------------------------------------------------------------
// den path
// ---------------------------------------------------------------------------
__global__ __launch_bounds__(256) void ka_kernel(const float* __restrict__ qk,
                                                 float* __restrict__ Ka) {
    int c = blockIdx.x, t = threadIdx.x;
    float s = 0.f;
    for (int l = 0; l < CH; ++l) s += qk[(c * CH + l) * QKN + 256 + t];
    Ka[c * AH + t] = s;
}

__global__ __launch_bounds__(256) void den2_kernel(const float* __restrict__ qk,
                                                   const float* __restrict__ Ka,
                                                   float* __restrict__ den) {
    int c = blockIdx.x, half = blockIdx.y, t = threadIdx.x;
    __shared__ float part[32][257];
    float run = 0.f;
    for (int cc = 0; cc < c; ++cc) run += Ka[cc * AH + t];
    int lbase = c * CH + half * 32;
    for (int l = c * CH; l < lbase; ++l) run += qk[l * QKN + 256 + t];
    for (int j = 0; j < 32; ++j) {
        int l = lbase + j;
        run += qk[l * QKN + 256 + t];
        part[j][t] = qk[l * QKN + t] * run;
    }
    __syncthreads();
    int l = t >> 3, h = t & 7;
    float s = 0.f;
#pragma unroll
    for (int a = 0; a < A_DIM; ++a) s += part[l][a * H_DIM + h];
    den[(lbase + l) * H_DIM + h] = s;
}

// ---------------------------------------------------------------------------
// LN1 over (D,H) + residual. qkv bf16 [l][h*D+d]; y bf16 [l][d*H+h].
// ---------------------------------------------------------------------------
__global__ __launch_bounds__(256) void ln1_kernel(const __hip_bfloat16* __restrict__ qkv,
                                                  const float* __restrict__ den,
                                                  const float* __restrict__ x,
                                                  const float* __restrict__ w,
                                                  const float* __restrict__ b,
                                                  __hip_bfloat16* __restrict__ y) {
    int l = blockIdx.x, tid = threadIdx.x;
    __shared__ float dsh[8];
    __shared__ float yl[DH];
    __shared__ float red[8];
    if (tid < 8) dsh[tid] = den[l * H_DIM + tid];
    __syncthreads();
    float t[16];
    float s = 0.f, s2 = 0.f;
#pragma unroll
    for (int j = 0; j < 16; ++j) {
        int e = j * 256 + tid;
        float val = (float)qkv[(size_t)l * DH + e] / dsh[e >> 9];
        t[j] = val;
        s += val;
        s2 += val * val;
    }
    for (int off = 32; off > 0; off >>= 1) {
        s += __shfl_down(s, off);
        s2 += __shfl_down(s2, off);
    }
    int lane = tid & 63, wid = tid >> 6;
    if (lane == 0) { red[wid] = s; red[4 + wid] = s2; }
    __syncthreads();
    float ts = red[0] + red[1] + red[2] + red[3];
    float t2 = red[4] + red[5] + red[6] + red[7];
    float mu = ts / (float)DH;
    float var = t2 / (float)DH - mu * mu;
    float rs = rsqrtf(var + EPS_LN);
#pragma unroll
    for (int j = 0; j < 16; ++j) {
        int e = j * 256 + tid;
        int h = e >> 9, d = e & 511;
        int dh = d * H_DIM + h;
        yl[dh] = x[l * D_DIM + d] + (t[j] - mu) * rs * w[dh] + b[dh];
    }
    __syncthreads();
#pragma unroll
    for (int j = 0; j < 16; ++j) {
        int e = j * 256 + tid;
        y[(size_t)l * DH + e] = (__hip_bfloat16)yl[e];
    }
}

// ---------------------------------------------------------------------------
// Launch
// ---------------------------------------------------------------------------
extern "C" void kernel_launch(void* const* d_in, const int* in_sizes, int n_in,
                              void* d_out, int out_size, void* d_ws, size_t ws_size,
                              hipStream_t stream) {
    const float* x     = (const float*)d_in[0];
    const float* ln0_w = (const float*)d_in[1];
    const float* ln0_b = (const float*)d_in[2];
    const float* ln1_w = (const float*)d_in[3];
    const float* ln1_b = (const float*)d_in[4];
    const float* qw    = (const float*)d_in[5];
    const float* qb    = (const float*)d_in[6];
    const float* kw    = (const float*)d_in[7];
    const float* kb    = (const float*)d_in[8];
    const float* vw    = (const float*)d_in[9];
    const float* vb    = (const float*)d_in[10];
    const float* w1    = (const float*)d_in[11];
    const float* b1    = (const float*)d_in[12];
    const float* w2    = (const float*)d_in[13];
    const float* b2    = (const float*)d_in[14];
    float* out = (float*)d_out;

    char* ws = (char*)d_ws;
    __hip_bfloat16* xn_bf = (__hip_bfloat16*)(ws + 0);         // 1 MB
    __hip_bfloat16* xbf   = (__hip_bfloat16*)(ws + 1048576);   // 1 MB
    __hip_bfloat16* qkwt  = (__hip_bfloat16*)(ws + 2097152);   // 0.5 MB
    __hip_bfloat16* vwt   = (__hip_bfloat16*)(ws + 2621440);   // 4 MB
    __hip_bfloat16* w1t   = (__hip_bfloat16*)(ws + 6815744);   // 16 MB
    __hip_bfloat16* w2t   = (__hip_bfloat16*)(ws + 23592960);  // 2 MB
    float* qk  = (float*)(ws + 25690112);                      // 2 MB
    __hip_bfloat16* vb16 = (__hip_bfloat16*)(ws + 27787264);   // 8 MB
    float* S   = (float*)(ws + 36175872);                      // 8 MB
    float* P   = (float*)(ws + 44564480);                      // 8 MB
    __hip_bfloat16* qkvb = (__hip_bfloat16*)(ws + 52953088);   // 8 MB
    float* Ka  = (float*)(ws + 61341696);                      // 16 KB
    float* den = (float*)(ws + 61358080);                      // 32 KB
    float* w1part = (float*)(ws + 61440000);                   // 16 MB (ends ~77.4 MB)
    __hip_bfloat16* y  = (__hip_bfloat16*)P;     // alias: P dead after passC
    __hip_bfloat16* h1 = (__hip_bfloat16*)S;     // alias: S dead after scanS
    float* w2part = (float*)qkvb;                // alias: qkvb dead after ln1

    // fused LN0 + weight converts
    prep_kernel<<<12544, 256, 0, stream>>>(x, ln0_w, ln0_b, qw, kw, vw, w1, w2,
                                           xn_bf, xbf, qkwt, vwt, w1t, w2t);
    // fused q|k projection -> qk [L][512] fp32
    gemm64<0, 0><<<dim3(QKN / 64, L_SEQ / 64, 1), 256, 0, stream>>>(
        xn_bf, qkwt, qb, kb, qk, L_SEQ, QKN, D_DIM, D_DIM);
    // v projection -> bf16 [L][h*D+d], XCD strip=8
    gemm64<1, 8><<<dim3((DH / 64) * (L_SEQ / 64), 1, 1), 256, 0, stream>>>(
        xbf, vwt, vb, nullptr, vb16, L_SEQ, DH, D_DIM, D_DIM);
    // chunked KV scan
    passA_kernel<<<dim3(NC, H_DIM, 2), 256, 0, stream>>>(qk, vb16, S);
    scanS_kernel<<<(A_DIM * H_DIM * D_DIM) / 256, 256, 0, stream>>>(S, P);
    passC_kernel<<<dim3(NC, H_DIM, 2), 256, 0, stream>>>(qk, vb16, P, qkvb);
    // den path
    ka_kernel<<<NC, 256, 0, stream>>>(qk, Ka);
    den2_kernel<<<dim3(NC, 2), 256, 0, stream>>>(qk, Ka, den);
    // LN1 + residual -> y bf16
    ln1_kernel<<<L_SEQ, 256, 0, stream>>>(qkvb, den, x, ln1_w, ln1_b, y);
    // w1: split-K=2, XCD strip=4 -> fp32 partials, then reduce -> h1 bf16
    gemm64<4, 4><<<dim3((F_DIM / 64) * (L_SEQ / 64), 1, 2), 256, 0, stream>>>(
        y, w1t, nullptr, nullptr, w1part, L_SEQ, F_DIM, DH, DH / 2);
    w1red<<<(L_SEQ * F_DIM) / 1024, 256, 0, stream>>>(w1part, b1, h1);
    // w2: split-K=4, XCD strip=1
    gemm64<4, 1><<<dim3((D_DIM / 64) * (L_SEQ / 64), 1, 4), 256, 0, stream>>>(
        h1, w2t, nullptr, nullptr, w2part, L_SEQ, D_DIM, F_DIM, F_DIM / 4);
    w2red<<<(L_SEQ * D_DIM) / 1024, 256, 0, stream>>>(w2part, b2, x, out);

    (void)in_sizes; (void)n_in; (void)out_size; (void)ws_size;
}